// Round 20
// baseline (72.204 us; speedup 1.0000x reference)
//
#include <hip/hip_runtime.h>
#include <hip/hip_bf16.h>

#define DEV __device__ __forceinline__

typedef __attribute__((ext_vector_type(8))) short bf16x8;
typedef __attribute__((ext_vector_type(4))) float f32x4;
typedef __attribute__((ext_vector_type(4))) unsigned short u16x4;

DEV float b2f(unsigned short u) {
    unsigned int v = ((unsigned int)u) << 16;
    float f; __builtin_memcpy(&f, &v, 4); return f;
}
DEV unsigned short f2b(float f) {            // RNE via bit-ops
    unsigned int v; __builtin_memcpy(&v, &f, 4);
    v = (v + 0x7fffu + ((v >> 16) & 1u)) >> 16;
    return (unsigned short)v;
}
DEV unsigned short f2b_hw(float f) {         // hardware cvt (RNE)
    __hip_bfloat16 h = __float2bfloat16(f);
    unsigned short u; __builtin_memcpy(&u, &h, 2); return u;
}
DEV float exp2raw(float x) { return __builtin_amdgcn_exp2f(x); }  // raw v_exp_f32

DEV f32x4 mfma16(bf16x8 a, bf16x8 b, f32x4 c) {
    return __builtin_amdgcn_mfma_f32_16x16x32_bf16(a, b, c, 0, 0, 0);
}

// global -> LDS async copy, 16B per lane; lds dest = uniform base + lane*16
DEV void stage16(const void* g, void* l) {
    __builtin_amdgcn_global_load_lds((const __attribute__((address_space(1))) void*)g,
                                     (__attribute__((address_space(3))) void*)l, 16, 0, 0);
}

#define WAIT_VM8()  asm volatile("s_waitcnt vmcnt(8)" ::: "memory")
#define WAIT_VM4()  asm volatile("s_waitcnt vmcnt(4)" ::: "memory")
#define WAIT_VM3()  asm volatile("s_waitcnt vmcnt(3)" ::: "memory")
#define WAIT_VM0()  asm volatile("s_waitcnt vmcnt(0)" ::: "memory")
#define WAIT_LGKM() asm volatile("s_waitcnt lgkmcnt(0)" ::: "memory")
#define BAR()       __builtin_amdgcn_s_barrier()
#define SCHED()     __builtin_amdgcn_sched_barrier(0)

constexpr float SCALE_L2E = 0.125f * 1.44269504088896340736f;  // DH^-0.5 * log2(e)

// ---------------------------------------------------------------------------
// K0: merged prep kernel, grid 2112 x 256 (unchanged from R18/R19).
// ---------------------------------------------------------------------------
__global__ __launch_bounds__(256) void k_prep(const float* __restrict__ x,
                                              const float* __restrict__ wq_s,
                                              const float* __restrict__ wk_s,
                                              const float* __restrict__ wv_r,
                                              const float* __restrict__ wq_r,
                                              const float* __restrict__ wk_ret,
                                              const float* __restrict__ w_out,
                                              unsigned short* __restrict__ xb,
                                              unsigned short* __restrict__ wt,
                                              unsigned short* __restrict__ wot,
                                              unsigned short* __restrict__ wkt)
{
    __shared__ float tl[32][33];
    if (blockIdx.x >= 1088) {
        const int U1 = 4096 * 512 / 4;               // x units (float4)
        const int U2 = 64 * 64 / 4;                  // wk_ret units
        const int total = U1 + U2;
        for (int u = (blockIdx.x - 1088) * 256 + threadIdx.x; u < total;
             u += 1024 * 256) {
            if (u < U1) {
                float4 v = ((const float4*)x)[u];
                u16x4 o = { f2b(v.x), f2b(v.y), f2b(v.z), f2b(v.w) };
                *(u16x4*)(xb + u * 4) = o;
            } else {
                int t = u - U1;
                float4 v = ((const float4*)wk_ret)[t];
                u16x4 o = { f2b(v.x), f2b(v.y), f2b(v.z), f2b(v.w) };
                *(u16x4*)(wkt + t * 4) = o;
            }
        }
        return;
    }
    int m = blockIdx.x;
    const float* src; unsigned short* dst;
    int base, srcld, kt, nt;
    if (m < 256)      { src = wq_s;  dst = wt;  base = 0;    srcld = 512; kt = m >> 4; nt = m & 15; }
    else if (m < 512) { m -= 256; src = wk_s;  dst = wt;  base = 512;  srcld = 512; kt = m >> 4; nt = m & 15; }
    else if (m < 576) { m -= 512; src = wv_r;  dst = wt;  base = 1024; srcld = 128; kt = m >> 2; nt = m & 3; }
    else if (m < 832) { m -= 576; src = wq_r;  dst = wt;  base = 1152; srcld = 512; kt = m >> 4; nt = m & 15; }
    else              { m -= 832; src = w_out; dst = wot; base = 0;    srcld = 512; kt = m >> 4; nt = m & 15; }

    const int r = threadIdx.x >> 5, c = threadIdx.x & 31;
#pragma unroll
    for (int s = 0; s < 4; ++s) {
        int rr = r + 8 * s;
        tl[rr][c] = src[(size_t)(kt * 32 + rr) * srcld + nt * 32 + c];
    }
    __syncthreads();
#pragma unroll
    for (int s = 0; s < 4; ++s) {
        int rr = r + 8 * s;
        dst[(size_t)(base + nt * 32 + rr) * 512 + kt * 32 + c] = f2b(tl[c][rr]);
    }
}

// ---------------------------------------------------------------------------
// K1/K3: staged GEMM  C[4096][N*] = A(bf16 [4096][512]) @ Bt(bf16 [N][512])^T
// Block = 4 waves (2x2); wave owns MB*16 rows x NB*16 cols.
//   EPI=0: MB=4,NB=4 -> 128x128, grid (32,13) = 416 blocks (single pass).
//   EPI=1: MB=2,NB=2 -> 64x64,  grid (64,8)  = 512 blocks = 2/CU + XCD remap.
// (unchanged from R19)
// ---------------------------------------------------------------------------
template<int EPI, int MB, int NB>
__global__ __launch_bounds__(256, 2) void k_gemm(const unsigned short* __restrict__ A,
                                                 const unsigned short* __restrict__ Bt,
                                                 unsigned short* __restrict__ qs,
                                                 unsigned short* __restrict__ ks,
                                                 unsigned short* __restrict__ rqb,
                                                 unsigned short* __restrict__ vt,
                                                 float* __restrict__ out)
{
    constexpr int ABYTES = 2 * MB * 16 * 128;        // A-tile bytes per buf
    constexpr int BBYTES = 2 * NB * 16 * 128;        // B-tile bytes per buf
    __shared__ unsigned char ab_lds[2 * (ABYTES + BBYTES)];

    const int tid = threadIdx.x;
    const int lane = tid & 63, wid = tid >> 6;
    const int lr = lane & 15, lg = lane >> 4;
    const int wr = wid >> 1, wc = wid & 1;

    int bx = blockIdx.x, by = blockIdx.y;
    if (EPI == 1) {
        int b = by * 64 + bx;
        bx = (b & 7) * 8 + ((b >> 3) & 7);
        by = b >> 6;
    }
    const int brow0 = bx * (2 * MB * 16);
    const int bcol0 = by * (2 * NB * 16);

    const int sub = lane >> 3;            // row within 8-row stripe
    const int chk = lane & 7;             // 16B chunk slot
    const int scs = chk ^ sub;            // swizzled source chunk

    const f32x4 z = {0.f, 0.f, 0.f, 0.f};
    f32x4 acc[MB][NB];
#pragma unroll
    for (int m = 0; m < MB; ++m)
#pragma unroll
        for (int n = 0; n < NB; ++n) acc[m][n] = z;

    const unsigned short* Ab = A + (size_t)brow0 * 512;

    auto STAGE = [&](int buf, int k0) {
        unsigned char* ab = ab_lds + buf * ABYTES;
        unsigned char* bb = ab_lds + 2 * ABYTES + buf * BBYTES;
#pragma unroll
        for (int ii = 0; ii < MB; ++ii) {
            int r0 = (wid * MB + ii) * 8;
            const unsigned short* g = Ab + (size_t)(r0 + sub) * 512 + k0 + scs * 8;
            stage16(g, ab + r0 * 128);
        }
#pragma unroll
        for (int ii = 0; ii < NB; ++ii) {
            int r0 = (wid * NB + ii) * 8;
            const unsigned short* g = Bt + (size_t)(bcol0 + r0 + sub) * 512 + k0 + scs * 8;
            stage16(g, bb + r0 * 128);
        }
    };

    auto COMPUTE = [&](const int cur) {
        const unsigned char* ab = ab_lds + cur * ABYTES;
        const unsigned char* bb = ab_lds + 2 * ABYTES + cur * BBYTES;
#pragma unroll
        for (int ksb = 0; ksb < 2; ++ksb) {
            const int c = ksb * 4 + lg;                       // k-chunk 0..7
            bf16x8 bfr[NB];
#pragma unroll
            for (int n = 0; n < NB; ++n) {
                int row = wc * (NB * 16) + n * 16 + lr;
                bfr[n] = *(const bf16x8*)(bb + row * 128 + ((c ^ (row & 7)) << 4));
            }
#pragma unroll
            for (int m = 0; m < MB; ++m) {
                int row = wr * (MB * 16) + m * 16 + lr;
                bf16x8 af = *(const bf16x8*)(ab + row * 128 + ((c ^ (row & 7)) << 4));
#pragma unroll
                for (int n = 0; n < NB; ++n)
                    acc[m][n] = mfma16(af, bfr[n], acc[m][n]);
            }
        }
    };

    auto WAIT_STEADY = [&]() {
        if constexpr (MB + NB == 4) { WAIT_VM4(); }
        else if constexpr (MB + NB == 8) { WAIT_VM8(); }
        else { WAIT_VM0(); }
    };

    STAGE(0, 0);
#pragma unroll 1
    for (int it = 0; it < 3; ++it) {
        STAGE(1, (2 * it + 1) * 64);
        WAIT_STEADY(); BAR(); SCHED();
        COMPUTE(0);
        WAIT_LGKM(); SCHED(); BAR(); SCHED();
        STAGE(0, (2 * it + 2) * 64);
        WAIT_STEADY(); BAR(); SCHED();
        COMPUTE(1);
        WAIT_LGKM(); SCHED(); BAR(); SCHED();
    }
    STAGE(1, 7 * 64);
    WAIT_STEADY(); BAR(); SCHED();
    COMPUTE(0);
    WAIT_LGKM(); SCHED(); BAR(); SCHED();
    WAIT_VM0(); BAR(); SCHED();
    COMPUTE(1);

#pragma unroll
    for (int m = 0; m < MB; ++m) {
#pragma unroll
        for (int n = 0; n < NB; ++n) {
#pragma unroll
            for (int i = 0; i < 4; ++i) {
                int gr = brow0 + wr * (MB * 16) + m * 16 + lg * 4 + i;
                int gc = bcol0 + wc * (NB * 16) + n * 16 + lr;
                float v = acc[m][n][i];
                if (EPI == 1) {
                    out[(size_t)gr * 512 + gc] = v;
                } else {
                    int b = gr >> 11, in = gr & 2047;
                    if (gc < 512) {
                        int s = gc >> 6, d = gc & 63;
                        qs[((b * 8 + s) * 2048 + in) * 64 + d] = f2b(v * SCALE_L2E);
                    } else if (gc < 1024) {
                        int cgc = gc - 512; int s = cgc >> 6, d = cgc & 63;
                        ks[((b * 8 + s) * 2048 + in) * 64 + d] = f2b(v);
                    } else if (gc < 1152) {
                        int cgc = gc - 1024;             // 0..127 = r*64+d
                        vt[(b * 128 + cgc) * 2048 + in] = f2b(v);
                    } else {
                        int cgc = gc - 1152; int s = cgc >> 6, d = cgc & 63;
                        rqb[((b * 8 + s) * 2048 + in) * 64 + d] = f2b(v * SCALE_L2E);
                    }
                }
            }
        }
    }
}

// ---------------------------------------------------------------------------
// K2: flash attention + fused retrieval composition.
// R20 = R19 + 3-buffer rotation -> ONE barrier per tile (was two):
//   iteration t: vmcnt(3) [tile t staged] -> s_barrier -> STAGE(t+2 into
//   buf[(t+2)%3]) -> COMPUTE(t from buf[t%3]).
// Race-freedom: STAGE(t+2) overwrites buf[(t-1)%3]; it is issued only after
// barrier-t, which every wave reaches only after COMPUTE(t-1) whose ds_reads
// are complete (lgkm waits precede the consuming MFMAs). vmcnt(3) steady:
// exactly one tile of stage (3 loads) stays in flight across the barrier.
// Unroll-by-3 keeps buffer indices literal. LDS 3x24KB = 72KB, 2 blocks/CU.
// ---------------------------------------------------------------------------
__global__ __launch_bounds__(512, 4) void k_attn(const unsigned short* __restrict__ qs,
                                                 const unsigned short* __restrict__ ks,
                                                 const unsigned short* __restrict__ rqb,
                                                 const unsigned short* __restrict__ vt,
                                                 const unsigned short* __restrict__ wkt,
                                                 unsigned short* __restrict__ ob)
{
    // 3 bufs x (K 8KB @ +0 | V 16KB @ +8192) = 72KB; merge region aliases
    // this after the main loop (all kv reads done + syncthreads).
    __shared__ unsigned char kv_lds[73728];

    const int tid = threadIdx.x;
    const int lane = tid & 63, wid = tid >> 6;        // wid 0..7
    const int lr = lane & 15, lg = lane >> 4;
    const int qsub = wid & 3, h = wid >> 2;
    const int braw = blockIdx.x;
    const int bid = (braw & 7) * 64 + (braw >> 3);    // XCD-locality remap (R19)
    const int bs = bid >> 5, qt = bid & 31;           // bs = b*8+s
    const int gb = bs >> 3, gs = bs & 7;
    const int qrow0 = qt * 64 + qsub * 16;

    const int sub = lane >> 3;                        // row within 8-row stripe
    const int scs = (lane & 7) ^ sub;                 // swizzled source chunk

    // Q fragments (B-operand layout: lane l&15 = qrow), in regs all kernel
    const unsigned short* qbase = qs + ((size_t)bs * 2048 + qrow0 + lr) * 64 + lg * 8;
    const bf16x8 q0 = *(const bf16x8*)(qbase);
    const bf16x8 q1 = *(const bf16x8*)(qbase + 32);

    const unsigned short* kbase = ks + (size_t)bs * 131072;     // [2048][64]
    const unsigned short* vbase = vt + (size_t)gb * 262144;     // [128][2048]

    const f32x4 z = {0.f, 0.f, 0.f, 0.f};

    float m_r = -3.0e38f;                             // running max, row lr
    float acc_l = 0.f;                                // lane-partial row sum
    f32x4 acc[8];                                     // O rows lg*4+i, d c8*16+lr
#pragma unroll
    for (int c8 = 0; c8 < 8; ++c8) acc[c8] = z;

    // --- permuted K-read offsets: rk(a) = h*32+(lr>>2)*8+a*4+(lr&3)
    const int rk0 = h * 32 + (lr >> 2) * 8 + (lr & 3);
    const int rk1 = rk0 + 4;
    const int ko0a = rk0 * 128 + ((lg ^ (rk0 & 7)) << 4);
    const int ko0b = rk0 * 128 + (((lg + 4) ^ (rk0 & 7)) << 4);
    const int ko1a = rk1 * 128 + ((lg ^ (rk1 & 7)) << 4);
    const int ko1b = rk1 * 128 + (((lg + 4) ^ (rk1 & 7)) << 4);
    // --- V-read offset: chunk (h*4+lg) ^ (lr&7), d-row (c8*16+lr)
    const int vx = lr * 128 + (((h * 4 + lg) ^ (lr & 7)) << 4);

    // --- stage stripes: 24 x 1KB per tile; wave stages 3 (s = wid*3+j)
    const unsigned short* sp[3];
    int step[3], loff[3];
#pragma unroll
    for (int j = 0; j < 3; ++j) {
        int s = wid * 3 + j;
        if (s < 8) { sp[j] = kbase + (size_t)(s * 8 + sub) * 64 + scs * 8;          step[j] = 4096; }
        else       { sp[j] = vbase + (size_t)((s - 8) * 8 + sub) * 2048 + scs * 8;  step[j] = 64;   }
        loff[j] = s * 1024;
    }

    auto STAGE = [&](const int buf) {
        unsigned char* base = kv_lds + buf * 24576;
#pragma unroll
        for (int j = 0; j < 3; ++j) {
            stage16(sp[j], base + loff[j]);
            sp[j] += step[j];
        }
    };

    auto COMPUTE = [&](const int cur) {
        const unsigned char* kb = kv_lds + cur * 24576;
        const unsigned char* vb = kb + 8192;

        // --- S^T = K_perm · Q^T  (2 calls x K-dim 64 via 2 mfma each)
        f32x4 s[2];
        __builtin_amdgcn_s_setprio(1);
        {
            bf16x8 kf0 = *(const bf16x8*)(kb + ko0a);
            bf16x8 kf1 = *(const bf16x8*)(kb + ko0b);
            f32x4 t = z;
            t = mfma16(kf0, q0, t);
            t = mfma16(kf1, q1, t);
            s[0] = t;
        }
        {
            bf16x8 kf0 = *(const bf16x8*)(kb + ko1a);
            bf16x8 kf1 = *(const bf16x8*)(kb + ko1b);
            f32x4 t = z;
            t = mfma16(kf0, q0, t);
            t = mfma16(kf1, q1, t);
            s[1] = t;
        }
        __builtin_amdgcn_s_setprio(0);

        // --- deferred-max online softmax (log2 units), row = lr per lane
        float lm = fmaxf(fmaxf(fmaxf(s[0][0], s[0][1]), fmaxf(s[0][2], s[0][3])),
                         fmaxf(fmaxf(s[1][0], s[1][1]), fmaxf(s[1][2], s[1][3])));
        if (__any(lm > m_r + 8.0f)) {
            float mx = fmaxf(lm, __shfl_xor(lm, 16));
            mx = fmaxf(mx, __shfl_xor(mx, 32));
            float m_new = fmaxf(m_r, mx);
            float alpha = exp2raw(m_r - m_new);
            float al[4];
#pragma unroll
            for (int i = 0; i < 4; ++i) al[i] = __shfl(alpha, lg * 4 + i, 16);
#pragma unroll
            for (int c8 = 0; c8 < 8; ++c8)
#pragma unroll
                for (int i = 0; i < 4; ++i) acc[c8][i] *= al[i];
            acc_l *= alpha;
            m_r = m_new;
        }

        // --- P = exp2(S - m); pack to PV A-fragment (keys h*32+lg*8+j)
        float p[8];
#pragma unroll
        for (int a = 0; a < 2; ++a)
#pragma unroll
            for (int i = 0; i < 4; ++i)
                p[a * 4 + i] = exp2raw(s[a][i] - m_r);
        acc_l += ((p[0] + p[1]) + (p[2] + p[3])) + ((p[4] + p[5]) + (p[6] + p[7]));
        unsigned int pu[4];
#pragma unroll
        for (int t2 = 0; t2 < 4; ++t2)
            asm("v_cvt_pk_bf16_f32 %0, %1, %2" : "=v"(pu[t2]) : "v"(p[2 * t2]), "v"(p[2 * t2 + 1]));
        bf16x8 pa;
        __builtin_memcpy(&pa, pu, 16);

        // --- PV: acc[c8] rows = qrows lg*4+i, cols d = c8*16+lr
        __builtin_amdgcn_s_setprio(1);
#pragma unroll
        for (int c8 = 0; c8 < 8; ++c8) {
            bf16x8 vf = *(const bf16x8*)(vb + c8 * 2048 + vx);
            acc[c8] = mfma16(pa, vf, acc[c8]);
        }
        __builtin_amdgcn_s_setprio(0);
    };

    STAGE(0);                                         // tile 0 -> buf0
    STAGE(1);                                         // tile 1 -> buf1

    // tiles 0..29 in triples; ONE barrier per tile, vmcnt(3) steady
#pragma unroll 1
    for (int it = 0; it < 10; ++it) {
        WAIT_VM3(); BAR(); SCHED();                   // tile 3it staged
        STAGE(2);                                     // tile 3it+2 -> buf2
        COMPUTE(0);                                   // tile 3it
        WAIT_VM3(); BAR(); SCHED();                   // tile 3it+1 staged
        STAGE(0);                                     // tile 3it+3 -> buf0
        COMPUTE(1);                                   // tile 3it+1
        WAIT_VM3(); BAR(); SCHED();                   // tile 3it+2 staged
        STAGE(1);                                     // tile 3it+4 -> buf1
        COMPUTE(2);                                   // tile 3it+2
    }
    // NOTE: iterations 9 issue STAGE for tiles 32/33? No — loop covers
    // t=0..29 and stages tiles up to 31 (t=29 stages t+2=31). Tiles 32/33
    // would be staged at it=9's 2nd/3rd steps... they are tiles 30+3=33?
    // Recount: it=9 handles t=27,28,29 staging tiles 29,30,31. Correct.
    WAIT_VM3(); BAR(); SCHED();                       // tile 30 staged
    COMPUTE(0);                                       // tile 30 (buf0)
    WAIT_VM0(); BAR(); SCHED();                       // tile 31 staged (drain)
    COMPUTE(1);                                       // tile 31 (buf1)

    // --- reduce row-sum l across the 4 lane-groups holding row lr
    float l2 = acc_l + __shfl_xor(acc_l, 16);
    float l_row = l2 + __shfl_xor(l2, 32);

    // --- merge halves through LDS (aliases dead kv region)
    __syncthreads();
    float* mrg = (float*)kv_lds;                      // [4][16][132] = 33792 B
    float* ml  = (float*)(kv_lds + 33792);            // [4][16][2]   = 512 B
    if (h == 1) {
#pragma unroll
        for (int c8 = 0; c8 < 8; ++c8)
#pragma unroll
            for (int i = 0; i < 4; ++i)
                mrg[(qsub * 16 + lg * 4 + i) * 132 + c8 * 16 + lr] = acc[c8][i];
        if (lane < 16) {
            ml[(qsub * 16 + lane) * 2 + 0] = m_r;     // row lr == lane
            ml[(qsub * 16 + lane) * 2 + 1] = l_row;
        }
    }
    __syncthreads();
    if (h == 1) return;

    // h==0: redistribute own m/l from row-lr layout to acc rows lg*4+i
    float m_own[4], l_own[4];
#pragma unroll
    for (int i = 0; i < 4; ++i) {
        m_own[i] = __shfl(m_r,  lg * 4 + i, 16);
        l_own[i] = __shfl(l_row, lg * 4 + i, 16);
    }

    // flash-merge partner partials
    float inv[4];
    f32x4 accM[8];
#pragma unroll
    for (int i = 0; i < 4; ++i) {
        float m_b = ml[(qsub * 16 + lg * 4 + i) * 2 + 0];
        float l_b = ml[(qsub * 16 + lg * 4 + i) * 2 + 1];
        float m_new = fmaxf(m_own[i], m_b);
        float fa = exp2raw(m_own[i] - m_new);
        float fb2 = exp2raw(m_b - m_new);
        inv[i] = 1.0f / (l_own[i] * fa + l_b * fb2);
#pragma unroll
        for (int c8 = 0; c8 < 8; ++c8)
            accM[c8][i] = acc[c8][i] * fa + mrg[(qsub * 16 + lg * 4 + i) * 132 + c8 * 16 + lr] * fb2;
    }

    // rq fragments (pre-scaled by DH^-0.5*log2e in k_gemm<0>)
    const unsigned short* rqbase = rqb + ((size_t)bs * 2048 + qrow0 + lr) * 64 + lg * 8;
    const bf16x8 rq0 = *(const bf16x8*)(rqbase);
    const bf16x8 rq1 = *(const bf16x8*)(rqbase + 32);

    // stage 2 via MFMA: T[q][d] = sum_dp rq[q][dp] * wk_ret[d][dp]
    f32x4 Tt[4];
#pragma unroll
    for (int ct = 0; ct < 4; ++ct) {
        bf16x8 wb0 = *(const bf16x8*)(wkt + (ct * 16 + lr) * 64 + lg * 8);
        bf16x8 wb1 = *(const bf16x8*)(wkt + (ct * 16 + lr) * 64 + 32 + lg * 8);
        f32x4 t = z;
        t = mfma16(rq0, wb0, t);
        t = mfma16(rq1, wb1, t);
        Tt[ct] = t;
    }

    // sim_r[row] = sum_{d} T[row][d] * retrN[row][r*64+d]   (log2 units)
    float w0v[4], w1v[4];
#pragma unroll
    for (int i = 0; i < 4; ++i) {
        float s0 = 0.f, s1 = 0.f;
#pragma unroll
        for (int ct = 0; ct < 4; ++ct) {
            s0 += Tt[ct][i] * accM[ct][i];
            s1 += Tt[ct][i] * accM[4 + ct][i];
        }
        s0 *= inv[i]; s1 *= inv[i];
        s0 += __shfl_xor(s0, 1, 16); s1 += __shfl_xor(s1, 1, 16);
        s0 += __shfl_xor(s0, 2, 16); s1 += __shfl_xor(s1, 2, 16);
        s0 += __shfl_xor(s0, 4, 16); s1 += __shfl_xor(s1, 4, 16);
        s0 += __shfl_xor(s0, 8, 16); s1 += __shfl_xor(s1, 8, 16);
        float mm = fmaxf(s0, s1);
        float e0 = exp2raw(s0 - mm), e1 = exp2raw(s1 - mm);
        float inw = 1.0f / (e0 + e1);
        w0v[i] = e0 * inw; w1v[i] = e1 * inw;
    }

    // --- combine r=2 and store ob[b][n][gs*64 + d]
#pragma unroll
    for (int ct = 0; ct < 4; ++ct) {
#pragma unroll
        for (int i = 0; i < 4; ++i) {
            float o = (w0v[i] * accM[ct][i] + w1v[i] * accM[4 + ct][i]) * inv[i];
            ob[((size_t)gb * 2048 + qrow0 + lg * 4 + i) * 512 + gs * 64 + ct * 16 + lr] = f2b_hw(o);
        }
    }
}

// ---------------------------------------------------------------------------
extern "C" void kernel_launch(void* const* d_in, const int* in_sizes, int n_in,
                              void* d_out, int out_size, void* d_ws, size_t ws_size,
                              hipStream_t stream)
{
    (void)in_sizes; (void)n_in; (void)out_size; (void)ws_size;
    const float* x      = (const float*)d_in[0];
    const float* wq_s   = (const float*)d_in[1];
    const float* wk_s   = (const float*)d_in[2];
    const float* wv_r   = (const float*)d_in[3];
    const float* wq_r   = (const float*)d_in[4];
    const float* wk_ret = (const float*)d_in[5];
    const float* w_out  = (const float*)d_in[6];

    char* ws = (char*)d_ws;                            // needs ~24.3 MB
    unsigned short* xb  = (unsigned short*)(ws + 0);          // [4096][512]
    unsigned short* wt  = (unsigned short*)(ws + 4194304);    // [1664][512]
    unsigned short* qsb = (unsigned short*)(ws + 5898240);    // [2][8][2048][64]
    unsigned short* ksb = (unsigned short*)(ws + 10092544);   // [2][8][2048][64]
    unsigned short* rqb = (unsigned short*)(ws + 14286848);   // [2][8][2048][64]
    unsigned short* vtb = (unsigned short*)(ws + 18481152);   // [2][128][2048]
    unsigned short* obb = (unsigned short*)(ws + 19529728);   // [2][2048][512]
    unsigned short* wot = (unsigned short*)(ws + 23724032);   // [512][512]
    unsigned short* wkt = (unsigned short*)(ws + 24248320);   // [64][64]

    hipLaunchKernelGGL(k_prep, dim3(2112), dim3(256), 0, stream,
                       x, wq_s, wk_s, wv_r, wq_r, wk_ret, w_out, xb, wt, wot, wkt);
    hipLaunchKernelGGL((k_gemm<0, 4, 4>), dim3(32, 13), dim3(256), 0, stream,
                       xb, wt, qsb, ksb, rqb, vtb, (float*)nullptr);
    hipLaunchKernelGGL(k_attn, dim3(512), dim3(512), 0, stream,
                       qsb, ksb, rqb, vtb, wkt, obb);
    hipLaunchKernelGGL((k_gemm<1, 2, 2>), dim3(64, 8), dim3(256), 0, stream,
                       obb, wot, (unsigned short*)nullptr, (unsigned short*)nullptr,
                       (unsigned short*)nullptr, (unsigned short*)nullptr, (float*)d_out);
}

// Round 21
// 69.702 us; speedup vs baseline: 1.0359x; 1.0359x over previous
//
#include <hip/hip_runtime.h>
#include <hip/hip_bf16.h>

#define DEV __device__ __forceinline__

typedef __attribute__((ext_vector_type(8))) short bf16x8;
typedef __attribute__((ext_vector_type(4))) float f32x4;
typedef __attribute__((ext_vector_type(4))) unsigned short u16x4;

DEV float b2f(unsigned short u) {
    unsigned int v = ((unsigned int)u) << 16;
    float f; __builtin_memcpy(&f, &v, 4); return f;
}
DEV unsigned short f2b(float f) {            // RNE via bit-ops
    unsigned int v; __builtin_memcpy(&v, &f, 4);
    v = (v + 0x7fffu + ((v >> 16) & 1u)) >> 16;
    return (unsigned short)v;
}
DEV unsigned short f2b_hw(float f) {         // hardware cvt (RNE)
    __hip_bfloat16 h = __float2bfloat16(f);
    unsigned short u; __builtin_memcpy(&u, &h, 2); return u;
}
DEV float exp2raw(float x) { return __builtin_amdgcn_exp2f(x); }  // raw v_exp_f32

DEV f32x4 mfma16(bf16x8 a, bf16x8 b, f32x4 c) {
    return __builtin_amdgcn_mfma_f32_16x16x32_bf16(a, b, c, 0, 0, 0);
}

// global -> LDS async copy, 16B per lane; lds dest = uniform base + lane*16
DEV void stage16(const void* g, void* l) {
    __builtin_amdgcn_global_load_lds((const __attribute__((address_space(1))) void*)g,
                                     (__attribute__((address_space(3))) void*)l, 16, 0, 0);
}

#define WAIT_VM8()  asm volatile("s_waitcnt vmcnt(8)" ::: "memory")
#define WAIT_VM4()  asm volatile("s_waitcnt vmcnt(4)" ::: "memory")
#define WAIT_VM3()  asm volatile("s_waitcnt vmcnt(3)" ::: "memory")
#define WAIT_VM0()  asm volatile("s_waitcnt vmcnt(0)" ::: "memory")
#define WAIT_LGKM() asm volatile("s_waitcnt lgkmcnt(0)" ::: "memory")
#define BAR()       __builtin_amdgcn_s_barrier()
#define SCHED()     __builtin_amdgcn_sched_barrier(0)

constexpr float SCALE_L2E = 0.125f * 1.44269504088896340736f;  // DH^-0.5 * log2(e)

// ---------------------------------------------------------------------------
// K0: merged prep kernel, grid 2112 x 256 (R18/R19 proven).
// ---------------------------------------------------------------------------
__global__ __launch_bounds__(256) void k_prep(const float* __restrict__ x,
                                              const float* __restrict__ wq_s,
                                              const float* __restrict__ wk_s,
                                              const float* __restrict__ wv_r,
                                              const float* __restrict__ wq_r,
                                              const float* __restrict__ wk_ret,
                                              const float* __restrict__ w_out,
                                              unsigned short* __restrict__ xb,
                                              unsigned short* __restrict__ wt,
                                              unsigned short* __restrict__ wot,
                                              unsigned short* __restrict__ wkt)
{
    __shared__ float tl[32][33];
    if (blockIdx.x >= 1088) {
        const int U1 = 4096 * 512 / 4;               // x units (float4)
        const int U2 = 64 * 64 / 4;                  // wk_ret units
        const int total = U1 + U2;
        for (int u = (blockIdx.x - 1088) * 256 + threadIdx.x; u < total;
             u += 1024 * 256) {
            if (u < U1) {
                float4 v = ((const float4*)x)[u];
                u16x4 o = { f2b(v.x), f2b(v.y), f2b(v.z), f2b(v.w) };
                *(u16x4*)(xb + u * 4) = o;
            } else {
                int t = u - U1;
                float4 v = ((const float4*)wk_ret)[t];
                u16x4 o = { f2b(v.x), f2b(v.y), f2b(v.z), f2b(v.w) };
                *(u16x4*)(wkt + t * 4) = o;
            }
        }
        return;
    }
    int m = blockIdx.x;
    const float* src; unsigned short* dst;
    int base, srcld, kt, nt;
    if (m < 256)      { src = wq_s;  dst = wt;  base = 0;    srcld = 512; kt = m >> 4; nt = m & 15; }
    else if (m < 512) { m -= 256; src = wk_s;  dst = wt;  base = 512;  srcld = 512; kt = m >> 4; nt = m & 15; }
    else if (m < 576) { m -= 512; src = wv_r;  dst = wt;  base = 1024; srcld = 128; kt = m >> 2; nt = m & 3; }
    else if (m < 832) { m -= 576; src = wq_r;  dst = wt;  base = 1152; srcld = 512; kt = m >> 4; nt = m & 15; }
    else              { m -= 832; src = w_out; dst = wot; base = 0;    srcld = 512; kt = m >> 4; nt = m & 15; }

    const int r = threadIdx.x >> 5, c = threadIdx.x & 31;
#pragma unroll
    for (int s = 0; s < 4; ++s) {
        int rr = r + 8 * s;
        tl[rr][c] = src[(size_t)(kt * 32 + rr) * srcld + nt * 32 + c];
    }
    __syncthreads();
#pragma unroll
    for (int s = 0; s < 4; ++s) {
        int rr = r + 8 * s;
        dst[(size_t)(base + nt * 32 + rr) * 512 + kt * 32 + c] = f2b(tl[c][rr]);
    }
}

// ---------------------------------------------------------------------------
// K1/K3: staged GEMM  C[4096][N*] = A(bf16 [4096][512]) @ Bt(bf16 [N][512])^T
// Block = 4 waves (2x2); wave owns MB*16 rows x NB*16 cols.
//   EPI=0: MB=4,NB=4 -> 128x128, grid (32,13) = 416 blocks (single pass).
//   EPI=1: MB=2,NB=2 -> 64x64,  grid (64,8)  = 512 blocks = 2/CU + XCD remap.
// ---------------------------------------------------------------------------
template<int EPI, int MB, int NB>
__global__ __launch_bounds__(256, 2) void k_gemm(const unsigned short* __restrict__ A,
                                                 const unsigned short* __restrict__ Bt,
                                                 unsigned short* __restrict__ qs,
                                                 unsigned short* __restrict__ ks,
                                                 unsigned short* __restrict__ rqb,
                                                 unsigned short* __restrict__ vt,
                                                 float* __restrict__ out)
{
    constexpr int ABYTES = 2 * MB * 16 * 128;        // A-tile bytes per buf
    constexpr int BBYTES = 2 * NB * 16 * 128;        // B-tile bytes per buf
    __shared__ unsigned char ab_lds[2 * (ABYTES + BBYTES)];

    const int tid = threadIdx.x;
    const int lane = tid & 63, wid = tid >> 6;
    const int lr = lane & 15, lg = lane >> 4;
    const int wr = wid >> 1, wc = wid & 1;

    int bx = blockIdx.x, by = blockIdx.y;
    if (EPI == 1) {
        int b = by * 64 + bx;
        bx = (b & 7) * 8 + ((b >> 3) & 7);
        by = b >> 6;
    }
    const int brow0 = bx * (2 * MB * 16);
    const int bcol0 = by * (2 * NB * 16);

    const int sub = lane >> 3;            // row within 8-row stripe
    const int chk = lane & 7;             // 16B chunk slot
    const int scs = chk ^ sub;            // swizzled source chunk

    const f32x4 z = {0.f, 0.f, 0.f, 0.f};
    f32x4 acc[MB][NB];
#pragma unroll
    for (int m = 0; m < MB; ++m)
#pragma unroll
        for (int n = 0; n < NB; ++n) acc[m][n] = z;

    const unsigned short* Ab = A + (size_t)brow0 * 512;

    auto STAGE = [&](int buf, int k0) {
        unsigned char* ab = ab_lds + buf * ABYTES;
        unsigned char* bb = ab_lds + 2 * ABYTES + buf * BBYTES;
#pragma unroll
        for (int ii = 0; ii < MB; ++ii) {
            int r0 = (wid * MB + ii) * 8;
            const unsigned short* g = Ab + (size_t)(r0 + sub) * 512 + k0 + scs * 8;
            stage16(g, ab + r0 * 128);
        }
#pragma unroll
        for (int ii = 0; ii < NB; ++ii) {
            int r0 = (wid * NB + ii) * 8;
            const unsigned short* g = Bt + (size_t)(bcol0 + r0 + sub) * 512 + k0 + scs * 8;
            stage16(g, bb + r0 * 128);
        }
    };

    auto COMPUTE = [&](const int cur) {
        const unsigned char* ab = ab_lds + cur * ABYTES;
        const unsigned char* bb = ab_lds + 2 * ABYTES + cur * BBYTES;
#pragma unroll
        for (int ksb = 0; ksb < 2; ++ksb) {
            const int c = ksb * 4 + lg;                       // k-chunk 0..7
            bf16x8 bfr[NB];
#pragma unroll
            for (int n = 0; n < NB; ++n) {
                int row = wc * (NB * 16) + n * 16 + lr;
                bfr[n] = *(const bf16x8*)(bb + row * 128 + ((c ^ (row & 7)) << 4));
            }
#pragma unroll
            for (int m = 0; m < MB; ++m) {
                int row = wr * (MB * 16) + m * 16 + lr;
                bf16x8 af = *(const bf16x8*)(ab + row * 128 + ((c ^ (row & 7)) << 4));
#pragma unroll
                for (int n = 0; n < NB; ++n)
                    acc[m][n] = mfma16(af, bfr[n], acc[m][n]);
            }
        }
    };

    auto WAIT_STEADY = [&]() {
        if constexpr (MB + NB == 4) { WAIT_VM4(); }
        else if constexpr (MB + NB == 8) { WAIT_VM8(); }
        else { WAIT_VM0(); }
    };

    STAGE(0, 0);
#pragma unroll 1
    for (int it = 0; it < 3; ++it) {
        STAGE(1, (2 * it + 1) * 64);
        WAIT_STEADY(); BAR(); SCHED();
        COMPUTE(0);
        WAIT_LGKM(); SCHED(); BAR(); SCHED();
        STAGE(0, (2 * it + 2) * 64);
        WAIT_STEADY(); BAR(); SCHED();
        COMPUTE(1);
        WAIT_LGKM(); SCHED(); BAR(); SCHED();
    }
    STAGE(1, 7 * 64);
    WAIT_STEADY(); BAR(); SCHED();
    COMPUTE(0);
    WAIT_LGKM(); SCHED(); BAR(); SCHED();
    WAIT_VM0(); BAR(); SCHED();
    COMPUTE(1);

#pragma unroll
    for (int m = 0; m < MB; ++m) {
#pragma unroll
        for (int n = 0; n < NB; ++n) {
#pragma unroll
            for (int i = 0; i < 4; ++i) {
                int gr = brow0 + wr * (MB * 16) + m * 16 + lg * 4 + i;
                int gc = bcol0 + wc * (NB * 16) + n * 16 + lr;
                float v = acc[m][n][i];
                if (EPI == 1) {
                    out[(size_t)gr * 512 + gc] = v;
                } else {
                    int b = gr >> 11, in = gr & 2047;
                    if (gc < 512) {
                        int s = gc >> 6, d = gc & 63;
                        qs[((b * 8 + s) * 2048 + in) * 64 + d] = f2b(v * SCALE_L2E);
                    } else if (gc < 1024) {
                        int cgc = gc - 512; int s = cgc >> 6, d = cgc & 63;
                        ks[((b * 8 + s) * 2048 + in) * 64 + d] = f2b(v);
                    } else if (gc < 1152) {
                        int cgc = gc - 1024;             // 0..127 = r*64+d
                        vt[(b * 128 + cgc) * 2048 + in] = f2b(v);
                    } else {
                        int cgc = gc - 1152; int s = cgc >> 6, d = cgc & 63;
                        rqb[((b * 8 + s) * 2048 + in) * 64 + d] = f2b(v * SCALE_L2E);
                    }
                }
            }
        }
    }
}

// ---------------------------------------------------------------------------
// K2: flash attention + fused retrieval composition.
// R21 = exact R19 (best measured: 41.4 µs, FETCH 8.3MB, VGPR 52, no spill):
// 8 waves x 16 q-rows, key-split h, swapped QK^T with permuted K (P lane-
// local), R13 swizzle, (512,4), 2-buffer counted-vmcnt raw-barrier pipeline,
// bijective XCD-locality remap bid = (b&7)*64 + (b>>3).
// ---------------------------------------------------------------------------
__global__ __launch_bounds__(512, 4) void k_attn(const unsigned short* __restrict__ qs,
                                                 const unsigned short* __restrict__ ks,
                                                 const unsigned short* __restrict__ rqb,
                                                 const unsigned short* __restrict__ vt,
                                                 const unsigned short* __restrict__ wkt,
                                                 unsigned short* __restrict__ ob)
{
    // 2 bufs x (K 8KB @ +0 | V 16KB @ +8192) = 48KB; merge region aliases
    // this after the main loop (all kv reads done + barrier).
    __shared__ unsigned char kv_lds[49152];

    const int tid = threadIdx.x;
    const int lane = tid & 63, wid = tid >> 6;        // wid 0..7
    const int lr = lane & 15, lg = lane >> 4;
    const int qsub = wid & 3, h = wid >> 2;
    const int braw = blockIdx.x;
    const int bid = (braw & 7) * 64 + (braw >> 3);    // XCD-locality remap
    const int bs = bid >> 5, qt = bid & 31;           // bs = b*8+s
    const int gb = bs >> 3, gs = bs & 7;
    const int qrow0 = qt * 64 + qsub * 16;

    const int sub = lane >> 3;                        // row within 8-row stripe
    const int scs = (lane & 7) ^ sub;                 // swizzled source chunk

    // Q fragments (B-operand layout: lane l&15 = qrow), in regs all kernel
    const unsigned short* qbase = qs + ((size_t)bs * 2048 + qrow0 + lr) * 64 + lg * 8;
    const bf16x8 q0 = *(const bf16x8*)(qbase);
    const bf16x8 q1 = *(const bf16x8*)(qbase + 32);

    const unsigned short* kbase = ks + (size_t)bs * 131072;     // [2048][64]
    const unsigned short* vbase = vt + (size_t)gb * 262144;     // [128][2048]

    const f32x4 z = {0.f, 0.f, 0.f, 0.f};

    float m_r = -3.0e38f;                             // running max, row lr
    float acc_l = 0.f;                                // lane-partial row sum
    f32x4 acc[8];                                     // O rows lg*4+i, d c8*16+lr
#pragma unroll
    for (int c8 = 0; c8 < 8; ++c8) acc[c8] = z;

    // --- permuted K-read offsets: rk(a) = h*32+(lr>>2)*8+a*4+(lr&3)
    const int rk0 = h * 32 + (lr >> 2) * 8 + (lr & 3);
    const int rk1 = rk0 + 4;
    const int ko0a = rk0 * 128 + ((lg ^ (rk0 & 7)) << 4);
    const int ko0b = rk0 * 128 + (((lg + 4) ^ (rk0 & 7)) << 4);
    const int ko1a = rk1 * 128 + ((lg ^ (rk1 & 7)) << 4);
    const int ko1b = rk1 * 128 + (((lg + 4) ^ (rk1 & 7)) << 4);
    // --- V-read offset: chunk (h*4+lg) ^ (lr&7), d-row (c8*16+lr)
    const int vx = lr * 128 + (((h * 4 + lg) ^ (lr & 7)) << 4);

    // --- stage stripes: 24 x 1KB per tile; wave stages 3 (s = wid*3+j)
    const unsigned short* sp[3];
    int step[3], loff[3];
#pragma unroll
    for (int j = 0; j < 3; ++j) {
        int s = wid * 3 + j;
        if (s < 8) { sp[j] = kbase + (size_t)(s * 8 + sub) * 64 + scs * 8;          step[j] = 4096; }
        else       { sp[j] = vbase + (size_t)((s - 8) * 8 + sub) * 2048 + scs * 8;  step[j] = 64;   }
        loff[j] = s * 1024;
    }

    auto STAGE = [&](const int buf) {
        unsigned char* base = kv_lds + buf * 24576;
#pragma unroll
        for (int j = 0; j < 3; ++j) {
            stage16(sp[j], base + loff[j]);
            sp[j] += step[j];
        }
    };

    auto COMPUTE = [&](const int cur) {
        const unsigned char* kb = kv_lds + cur * 24576;
        const unsigned char* vb = kb + 8192;

        // --- S^T = K_perm · Q^T  (2 calls x K-dim 64 via 2 mfma each)
        f32x4 s[2];
        __builtin_amdgcn_s_setprio(1);
        {
            bf16x8 kf0 = *(const bf16x8*)(kb + ko0a);
            bf16x8 kf1 = *(const bf16x8*)(kb + ko0b);
            f32x4 t = z;
            t = mfma16(kf0, q0, t);
            t = mfma16(kf1, q1, t);
            s[0] = t;
        }
        {
            bf16x8 kf0 = *(const bf16x8*)(kb + ko1a);
            bf16x8 kf1 = *(const bf16x8*)(kb + ko1b);
            f32x4 t = z;
            t = mfma16(kf0, q0, t);
            t = mfma16(kf1, q1, t);
            s[1] = t;
        }
        __builtin_amdgcn_s_setprio(0);

        // --- deferred-max online softmax (log2 units), row = lr per lane
        float lm = fmaxf(fmaxf(fmaxf(s[0][0], s[0][1]), fmaxf(s[0][2], s[0][3])),
                         fmaxf(fmaxf(s[1][0], s[1][1]), fmaxf(s[1][2], s[1][3])));
        if (__any(lm > m_r + 8.0f)) {
            float mx = fmaxf(lm, __shfl_xor(lm, 16));
            mx = fmaxf(mx, __shfl_xor(mx, 32));
            float m_new = fmaxf(m_r, mx);
            float alpha = exp2raw(m_r - m_new);
            float al[4];
#pragma unroll
            for (int i = 0; i < 4; ++i) al[i] = __shfl(alpha, lg * 4 + i, 16);
#pragma unroll
            for (int c8 = 0; c8 < 8; ++c8)
#pragma unroll
                for (int i = 0; i < 4; ++i) acc[c8][i] *= al[i];
            acc_l *= alpha;
            m_r = m_new;
        }

        // --- P = exp2(S - m); pack to PV A-fragment (keys h*32+lg*8+j)
        float p[8];
#pragma unroll
        for (int a = 0; a < 2; ++a)
#pragma unroll
            for (int i = 0; i < 4; ++i)
                p[a * 4 + i] = exp2raw(s[a][i] - m_r);
        acc_l += ((p[0] + p[1]) + (p[2] + p[3])) + ((p[4] + p[5]) + (p[6] + p[7]));
        unsigned int pu[4];
#pragma unroll
        for (int t2 = 0; t2 < 4; ++t2)
            asm("v_cvt_pk_bf16_f32 %0, %1, %2" : "=v"(pu[t2]) : "v"(p[2 * t2]), "v"(p[2 * t2 + 1]));
        bf16x8 pa;
        __builtin_memcpy(&pa, pu, 16);

        // --- PV: acc[c8] rows = qrows lg*4+i, cols d = c8*16+lr
        __builtin_amdgcn_s_setprio(1);
#pragma unroll
        for (int c8 = 0; c8 < 8; ++c8) {
            bf16x8 vf = *(const bf16x8*)(vb + c8 * 2048 + vx);
            acc[c8] = mfma16(pa, vf, acc[c8]);
        }
        __builtin_amdgcn_s_setprio(0);
    };

    STAGE(0);                                         // tile 0 -> buf0

#pragma unroll 1
    for (int it = 0; it < 15; ++it) {
        STAGE(1);                                     // tile 2it+1
        WAIT_VM3(); BAR(); SCHED();
        COMPUTE(0);                                   // tile 2it
        WAIT_LGKM(); SCHED(); BAR(); SCHED();
        STAGE(0);                                     // tile 2it+2
        WAIT_VM3(); BAR(); SCHED();
        COMPUTE(1);                                   // tile 2it+1
        WAIT_LGKM(); SCHED(); BAR(); SCHED();
    }
    STAGE(1);                                         // tile 31
    WAIT_VM3(); BAR(); SCHED();
    COMPUTE(0);                                       // tile 30
    WAIT_LGKM(); SCHED(); BAR(); SCHED();
    WAIT_VM0(); BAR(); SCHED();
    COMPUTE(1);                                       // tile 31

    // --- reduce row-sum l across the 4 lane-groups holding row lr
    float l2 = acc_l + __shfl_xor(acc_l, 16);
    float l_row = l2 + __shfl_xor(l2, 32);

    // --- merge halves through LDS (aliases dead kv region)
    __syncthreads();
    float* mrg = (float*)kv_lds;                      // [4][16][132] = 33792 B
    float* ml  = (float*)(kv_lds + 33792);            // [4][16][2]   = 512 B
    if (h == 1) {
#pragma unroll
        for (int c8 = 0; c8 < 8; ++c8)
#pragma unroll
            for (int i = 0; i < 4; ++i)
                mrg[(qsub * 16 + lg * 4 + i) * 132 + c8 * 16 + lr] = acc[c8][i];
        if (lane < 16) {
            ml[(qsub * 16 + lane) * 2 + 0] = m_r;     // row lr == lane
            ml[(qsub * 16 + lane) * 2 + 1] = l_row;
        }
    }
    __syncthreads();
    if (h == 1) return;

    // h==0: redistribute own m/l from row-lr layout to acc rows lg*4+i
    float m_own[4], l_own[4];
#pragma unroll
    for (int i = 0; i < 4; ++i) {
        m_own[i] = __shfl(m_r,  lg * 4 + i, 16);
        l_own[i] = __shfl(l_row, lg * 4 + i, 16);
    }

    // flash-merge partner partials
    float inv[4];
    f32x4 accM[8];
#pragma unroll
    for (int i = 0; i < 4; ++i) {
        float m_b = ml[(qsub * 16 + lg * 4 + i) * 2 + 0];
        float l_b = ml[(qsub * 16 + lg * 4 + i) * 2 + 1];
        float m_new = fmaxf(m_own[i], m_b);
        float fa = exp2raw(m_own[i] - m_new);
        float fb2 = exp2raw(m_b - m_new);
        inv[i] = 1.0f / (l_own[i] * fa + l_b * fb2);
#pragma unroll
        for (int c8 = 0; c8 < 8; ++c8)
            accM[c8][i] = acc[c8][i] * fa + mrg[(qsub * 16 + lg * 4 + i) * 132 + c8 * 16 + lr] * fb2;
    }

    // rq fragments (pre-scaled by DH^-0.5*log2e in k_gemm<0>)
    const unsigned short* rqbase = rqb + ((size_t)bs * 2048 + qrow0 + lr) * 64 + lg * 8;
    const bf16x8 rq0 = *(const bf16x8*)(rqbase);
    const bf16x8 rq1 = *(const bf16x8*)(rqbase + 32);

    // stage 2 via MFMA: T[q][d] = sum_dp rq[q][dp] * wk_ret[d][dp]
    f32x4 Tt[4];
#pragma unroll
    for (int ct = 0; ct < 4; ++ct) {
        bf16x8 wb0 = *(const bf16x8*)(wkt + (ct * 16 + lr) * 64 + lg * 8);
        bf16x8 wb1 = *(const bf16x8*)(wkt + (ct * 16 + lr) * 64 + 32 + lg * 8);
        f32x4 t = z;
        t = mfma16(rq0, wb0, t);
        t = mfma16(rq1, wb1, t);
        Tt[ct] = t;
    }

    // sim_r[row] = sum_{d} T[row][d] * retrN[row][r*64+d]   (log2 units)
    float w0v[4], w1v[4];
#pragma unroll
    for (int i = 0; i < 4; ++i) {
        float s0 = 0.f, s1 = 0.f;
#pragma unroll
        for (int ct = 0; ct < 4; ++ct) {
            s0 += Tt[ct][i] * accM[ct][i];
            s1 += Tt[ct][i] * accM[4 + ct][i];
        }
        s0 *= inv[i]; s1 *= inv[i];
        s0 += __shfl_xor(s0, 1, 16); s1 += __shfl_xor(s1, 1, 16);
        s0 += __shfl_xor(s0, 2, 16); s1 += __shfl_xor(s1, 2, 16);
        s0 += __shfl_xor(s0, 4, 16); s1 += __shfl_xor(s1, 4, 16);
        s0 += __shfl_xor(s0, 8, 16); s1 += __shfl_xor(s1, 8, 16);
        float mm = fmaxf(s0, s1);
        float e0 = exp2raw(s0 - mm), e1 = exp2raw(s1 - mm);
        float inw = 1.0f / (e0 + e1);
        w0v[i] = e0 * inw; w1v[i] = e1 * inw;
    }

    // --- combine r=2 and store ob[b][n][gs*64 + d]
#pragma unroll
    for (int ct = 0; ct < 4; ++ct) {
#pragma unroll
        for (int i = 0; i < 4; ++i) {
            float o = (w0v[i] * accM[ct][i] + w1v[i] * accM[4 + ct][i]) * inv[i];
            ob[((size_t)gb * 2048 + qrow0 + lg * 4 + i) * 512 + gs * 64 + ct * 16 + lr] = f2b_hw(o);
        }
    }
}

// ---------------------------------------------------------------------------
extern "C" void kernel_launch(void* const* d_in, const int* in_sizes, int n_in,
                              void* d_out, int out_size, void* d_ws, size_t ws_size,
                              hipStream_t stream)
{
    (void)in_sizes; (void)n_in; (void)out_size; (void)ws_size;
    const float* x      = (const float*)d_in[0];
    const float* wq_s   = (const float*)d_in[1];
    const float* wk_s   = (const float*)d_in[2];
    const float* wv_r   = (const float*)d_in[3];
    const float* wq_r   = (const float*)d_in[4];
    const float* wk_ret = (const float*)d_in[5];
    const float* w_out  = (const float*)d_in[6];

    char* ws = (char*)d_ws;                            // needs ~24.3 MB
    unsigned short* xb  = (unsigned short*)(ws + 0);          // [4096][512]
    unsigned short* wt  = (unsigned short*)(ws + 4194304);    // [1664][512]
    unsigned short* qsb = (unsigned short*)(ws + 5898240);    // [2][8][2048][64]
    unsigned short* ksb = (unsigned short*)(ws + 10092544);   // [2][8][2048][64]
    unsigned short* rqb = (unsigned short*)(ws + 14286848);   // [2][8][2048][64]
    unsigned short* vtb = (unsigned short*)(ws + 18481152);   // [2][128][2048]
    unsigned short* obb = (unsigned short*)(ws + 19529728);   // [2][2048][512]
    unsigned short* wot = (unsigned short*)(ws + 23724032);   // [512][512]
    unsigned short* wkt = (unsigned short*)(ws + 24248320);   // [64][64]

    hipLaunchKernelGGL(k_prep, dim3(2112), dim3(256), 0, stream,
                       x, wq_s, wk_s, wv_r, wq_r, wk_ret, w_out, xb, wt, wot, wkt);
    hipLaunchKernelGGL((k_gemm<0, 4, 4>), dim3(32, 13), dim3(256), 0, stream,
                       xb, wt, qsb, ksb, rqb, vtb, (float*)nullptr);
    hipLaunchKernelGGL(k_attn, dim3(512), dim3(512), 0, stream,
                       qsb, ksb, rqb, vtb, wkt, obb);
    hipLaunchKernelGGL((k_gemm<1, 2, 2>), dim3(64, 8), dim3(256), 0, stream,
                       obb, wot, (unsigned short*)nullptr, (unsigned short*)nullptr,
                       (unsigned short*)nullptr, (unsigned short*)nullptr, (float*)d_out);
}